// Round 2
// baseline (102.782 us; speedup 1.0000x reference)
//
#include <hip/hip_runtime.h>
#include <hip/hip_bf16.h>
#include <stdint.h>

typedef __attribute__((ext_vector_type(8))) short bf16x8;
typedef __attribute__((ext_vector_type(4))) float f32x4;

__device__ __forceinline__ short f2bf(float x) {
    uint32_t u = __builtin_bit_cast(uint32_t, x);
    uint32_t r = (u + 0x7FFFu + ((u >> 16) & 1u)) >> 16;
    return (short)r;
}

// ---------------------------------------------------------------------------
// Kernel C: repack Wq (1024x48 f32) into bf16 B-fragment layout:
// wfrag[((ks*3+nf)*64 + lane)*8 + j] = Wq[k][n], k=ks*32+(lane>>4)*8+j, n=nf*16+(lane&15)
// ---------------------------------------------------------------------------
__global__ __launch_bounds__(256) void prep_wfrag(const float* __restrict__ Wq,
                                                  short* __restrict__ wfrag) {
    int idx = blockIdx.x * 256 + threadIdx.x;   // 0..49151
    int j    = idx & 7;
    int lane = (idx >> 3) & 63;
    int grp  = idx >> 9;          // ks*3+nf, 0..95
    int nf   = grp % 3;
    int ks   = grp / 3;
    int k = ks * 32 + ((lane >> 4) << 3) + j;
    int n = nf * 16 + (lane & 15);
    wfrag[idx] = f2bf(Wq[k * 48 + n]);
}

// ---------------------------------------------------------------------------
// Kernel A: qk = Q @ Wq + bq  (M=32768, N=48, K=1024), MFMA 16x16x32 bf16.
// Each wave: 16 rows x 48 cols. A-frags read straight from global f32.
// Epilogue scatter-stores bf16 weights into wgt[b][h][k][d].
// ---------------------------------------------------------------------------
__global__ __launch_bounds__(256) void qk_gemm(const float* __restrict__ Q,
                                               const short* __restrict__ wfrag,
                                               const float* __restrict__ bq,
                                               short* __restrict__ wgt) {
    const int l  = threadIdx.x & 63;
    const int w  = threadIdx.x >> 6;
    const int lr = l & 15;
    const int lk = l >> 4;
    const int row0 = blockIdx.x * 64 + w * 16;   // this wave's 16 rows

    f32x4 acc[3];
    acc[0] = (f32x4){0.f, 0.f, 0.f, 0.f};
    acc[1] = acc[0];
    acc[2] = acc[0];

    const float* qbase = Q + (size_t)(row0 + lr) * 1024 + lk * 8;

    #pragma unroll 4
    for (int ks = 0; ks < 32; ++ks) {
        const float* p = qbase + ks * 32;
        f32x4 q0 = *(const f32x4*)p;
        f32x4 q1 = *(const f32x4*)(p + 4);
        bf16x8 a;
        a[0] = f2bf(q0[0]); a[1] = f2bf(q0[1]); a[2] = f2bf(q0[2]); a[3] = f2bf(q0[3]);
        a[4] = f2bf(q1[0]); a[5] = f2bf(q1[1]); a[6] = f2bf(q1[2]); a[7] = f2bf(q1[3]);
        const bf16x8* wp = (const bf16x8*)(wfrag + (size_t)ks * 1536 + l * 8);
        acc[0] = __builtin_amdgcn_mfma_f32_16x16x32_bf16(a, wp[0],   acc[0], 0, 0, 0);
        acc[1] = __builtin_amdgcn_mfma_f32_16x16x32_bf16(a, wp[64],  acc[1], 0, 0, 0);
        acc[2] = __builtin_amdgcn_mfma_f32_16x16x32_bf16(a, wp[128], acc[2], 0, 0, 0);
    }

    // C frag: col n = nf*16+lr, row = row0 + lk*4 + r
    #pragma unroll
    for (int nf = 0; nf < 3; ++nf) {
        int n = nf * 16 + lr;
        float bias = bq[n];
        int t  = n / 3;
        int kk = n - t * 3;
        #pragma unroll
        for (int r = 0; r < 4; ++r) {
            int row = row0 + lk * 4 + r;
            int b   = row >> 10;
            int rb  = row & 1023;
            int h   = rb >> 6;
            int sp  = rb & 63;
            int d   = sp * 16 + t;
            wgt[((((b << 4) + h) * 3 + kk) << 10) + d] = f2bf(acc[nf][r] + bias);
        }
    }
}

// ---------------------------------------------------------------------------
// Kernel B v2: per-batch conv-as-GEMM, NO LDS, NO barriers.
// out[h,s] = sum_{k,d} wgt[b,h,k,d]*key[b,s+k-1,d]
// Each wave: 16 h x 16 s tile, K'=3072. B-frags (keys, f32->bf16) and A-frags
// (wgt bf16) read directly from global; L1/L2 absorb the 3x k-tap reuse.
// 512 blocks x 256 threads = 2048 independent waves.
// ---------------------------------------------------------------------------
__global__ __launch_bounds__(256) void conv_mfma(const float* __restrict__ Key,
                                                 const short* __restrict__ wgt,
                                                 float* __restrict__ out) {
    const int b   = blockIdx.x >> 4;
    const int s0  = (blockIdx.x & 15) * 64;
    const int l   = threadIdx.x & 63;
    const int w   = threadIdx.x >> 6;      // 0..3
    const int lr  = l & 15;
    const int lk  = l >> 4;

    const int s = s0 + w * 16 + lr;        // this lane's B-frag column
    const float* keyB = Key + ((size_t)b << 20);
    const short* wgtB = wgt + (size_t)b * 49152;

    const bool ok0 = (s - 1 >= 0);
    const bool ok2 = (s + 1 < 1024);
    const float* pk0 = keyB + ((size_t)(ok0 ? s - 1 : 0) << 10) + lk * 8;
    const float* pk1 = keyB + ((size_t)s << 10) + lk * 8;
    const float* pk2 = keyB + ((size_t)(ok2 ? s + 1 : 0) << 10) + lk * 8;
    const short* pa  = wgtB + (lr * 3 << 10) + lk * 8;

    f32x4 acc = (f32x4){0.f, 0.f, 0.f, 0.f};
    const f32x4 z = (f32x4){0.f, 0.f, 0.f, 0.f};

    #pragma unroll 2
    for (int c = 0; c < 32; ++c) {
        const int off = c * 32;
        // k = 0 (key row s-1)
        {
            f32x4 v0 = ok0 ? *(const f32x4*)(pk0 + off) : z;
            f32x4 v1 = ok0 ? *(const f32x4*)(pk0 + off + 4) : z;
            bf16x8 kv;
            kv[0]=f2bf(v0[0]); kv[1]=f2bf(v0[1]); kv[2]=f2bf(v0[2]); kv[3]=f2bf(v0[3]);
            kv[4]=f2bf(v1[0]); kv[5]=f2bf(v1[1]); kv[6]=f2bf(v1[2]); kv[7]=f2bf(v1[3]);
            bf16x8 a = *(const bf16x8*)(pa + off);
            acc = __builtin_amdgcn_mfma_f32_16x16x32_bf16(a, kv, acc, 0, 0, 0);
        }
        // k = 1 (key row s)
        {
            f32x4 v0 = *(const f32x4*)(pk1 + off);
            f32x4 v1 = *(const f32x4*)(pk1 + off + 4);
            bf16x8 kv;
            kv[0]=f2bf(v0[0]); kv[1]=f2bf(v0[1]); kv[2]=f2bf(v0[2]); kv[3]=f2bf(v0[3]);
            kv[4]=f2bf(v1[0]); kv[5]=f2bf(v1[1]); kv[6]=f2bf(v1[2]); kv[7]=f2bf(v1[3]);
            bf16x8 a = *(const bf16x8*)(pa + (1 << 10) + off);
            acc = __builtin_amdgcn_mfma_f32_16x16x32_bf16(a, kv, acc, 0, 0, 0);
        }
        // k = 2 (key row s+1)
        {
            f32x4 v0 = ok2 ? *(const f32x4*)(pk2 + off) : z;
            f32x4 v1 = ok2 ? *(const f32x4*)(pk2 + off + 4) : z;
            bf16x8 kv;
            kv[0]=f2bf(v0[0]); kv[1]=f2bf(v0[1]); kv[2]=f2bf(v0[2]); kv[3]=f2bf(v0[3]);
            kv[4]=f2bf(v1[0]); kv[5]=f2bf(v1[1]); kv[6]=f2bf(v1[2]); kv[7]=f2bf(v1[3]);
            bf16x8 a = *(const bf16x8*)(pa + (2 << 10) + off);
            acc = __builtin_amdgcn_mfma_f32_16x16x32_bf16(a, kv, acc, 0, 0, 0);
        }
    }

    // C frag: col = s (lr-based), row = h = lk*4 + r
    #pragma unroll
    for (int r = 0; r < 4; ++r) {
        int h = lk * 4 + r;
        out[(((b << 4) + h) << 10) + s] = acc[r];
    }
}

extern "C" void kernel_launch(void* const* d_in, const int* in_sizes, int n_in,
                              void* d_out, int out_size, void* d_ws, size_t ws_size,
                              hipStream_t stream) {
    const float* Q  = (const float*)d_in[0];
    const float* K  = (const float*)d_in[1];
    const float* Wq = (const float*)d_in[4];
    const float* bq = (const float*)d_in[5];
    float* outp = (float*)d_out;

    short* wfrag = (short*)d_ws;                      // 98304 B
    short* wgt   = (short*)((char*)d_ws + 98304);     // 3145728 B

    hipLaunchKernelGGL(prep_wfrag, dim3(192), dim3(256), 0, stream, Wq, wfrag);
    hipLaunchKernelGGL(qk_gemm,    dim3(512), dim3(256), 0, stream, Q, wfrag, bq, wgt);
    hipLaunchKernelGGL(conv_mfma,  dim3(512), dim3(256), 0, stream, K, wgt, outp);
}

// Round 3
// 66.814 us; speedup vs baseline: 1.5383x; 1.5383x over previous
//
#include <hip/hip_runtime.h>
#include <hip/hip_bf16.h>
#include <stdint.h>

typedef __attribute__((ext_vector_type(8))) short bf16x8;
typedef __attribute__((ext_vector_type(4))) float f32x4;

__device__ __forceinline__ short f2bf(float x) {
    uint32_t u = __builtin_bit_cast(uint32_t, x);
    uint32_t r = (u + 0x7FFFu + ((u >> 16) & 1u)) >> 16;
    return (short)r;
}

__device__ __forceinline__ bf16x8 pack8(f32x4 a, f32x4 b) {
    bf16x8 r;
    r[0] = f2bf(a[0]); r[1] = f2bf(a[1]); r[2] = f2bf(a[2]); r[3] = f2bf(a[3]);
    r[4] = f2bf(b[0]); r[5] = f2bf(b[1]); r[6] = f2bf(b[2]); r[7] = f2bf(b[3]);
    return r;
}

// ---------------------------------------------------------------------------
// Kernel C: repack Wq (1024x48 f32) into bf16 B-fragment layout.
// ---------------------------------------------------------------------------
__global__ __launch_bounds__(256) void prep_wfrag(const float* __restrict__ Wq,
                                                  short* __restrict__ wfrag) {
    int idx = blockIdx.x * 256 + threadIdx.x;   // 0..49151
    int j    = idx & 7;
    int lane = (idx >> 3) & 63;
    int grp  = idx >> 9;          // ks*3+nf
    int nf   = grp % 3;
    int ks   = grp / 3;
    int k = ks * 32 + ((lane >> 4) << 3) + j;
    int n = nf * 16 + (lane & 15);
    wfrag[idx] = f2bf(Wq[k * 48 + n]);
}

// ---------------------------------------------------------------------------
// Kernel A: qk = Q @ Wq + bq  (M=32768, N=48, K=1024), MFMA 16x16x32 bf16.
// Epilogue scatter-stores bf16 weights into A-frag-friendly layout:
//   wgtA[b][k][dg(128)][h(16)][8]  (dg = d>>3, j = d&7)
// ---------------------------------------------------------------------------
__global__ __launch_bounds__(256) void qk_gemm(const float* __restrict__ Q,
                                               const short* __restrict__ wfrag,
                                               const float* __restrict__ bq,
                                               short* __restrict__ wgtA) {
    const int l  = threadIdx.x & 63;
    const int w  = threadIdx.x >> 6;
    const int lr = l & 15;
    const int lk = l >> 4;
    const int row0 = blockIdx.x * 64 + w * 16;

    f32x4 acc[3];
    acc[0] = (f32x4){0.f, 0.f, 0.f, 0.f};
    acc[1] = acc[0];
    acc[2] = acc[0];

    const float* qbase = Q + (size_t)(row0 + lr) * 1024 + lk * 8;

    #pragma unroll 4
    for (int ks = 0; ks < 32; ++ks) {
        const float* p = qbase + ks * 32;
        f32x4 q0 = *(const f32x4*)p;
        f32x4 q1 = *(const f32x4*)(p + 4);
        bf16x8 a = pack8(q0, q1);
        const bf16x8* wp = (const bf16x8*)(wfrag + (size_t)ks * 1536 + l * 8);
        acc[0] = __builtin_amdgcn_mfma_f32_16x16x32_bf16(a, wp[0],   acc[0], 0, 0, 0);
        acc[1] = __builtin_amdgcn_mfma_f32_16x16x32_bf16(a, wp[64],  acc[1], 0, 0, 0);
        acc[2] = __builtin_amdgcn_mfma_f32_16x16x32_bf16(a, wp[128], acc[2], 0, 0, 0);
    }

    #pragma unroll
    for (int nf = 0; nf < 3; ++nf) {
        int n = nf * 16 + lr;
        float bias = bq[n];
        int t  = n / 3;
        int kk = n - t * 3;
        #pragma unroll
        for (int r = 0; r < 4; ++r) {
            int row = row0 + lk * 4 + r;
            int b   = row >> 10;
            int h   = (row >> 6) & 15;
            int sp  = row & 63;
            int dg  = sp * 2 + (t >> 3);
            int j   = t & 7;
            wgtA[(((size_t)(b * 3 + kk) * 128 + dg) << 7) + h * 8 + j] = f2bf(acc[nf][r] + bias);
        }
    }
}

// ---------------------------------------------------------------------------
// Kernel B v3: conv-as-GEMM, LDS-staged keys, double-buffered, async-split
// staging (T14). Grid: 32 b x 16 s-tiles x 2 d-halves = 1024 blocks, 256 thr.
// Each wave: 16h x 16s, K'=1536 (its d-half, 8 chunks of 64 d).
// Partial sums atomicAdd'ed into zeroed out.
// ---------------------------------------------------------------------------
__global__ __launch_bounds__(256, 4) void conv_mfma(const float* __restrict__ Key,
                                                    const short* __restrict__ wgtA,
                                                    float* __restrict__ out) {
    __shared__ short klds[2][66][72];   // 19008 B, row shift 4 banks: conflict-free
    const int blk = blockIdx.x;
    const int kc  = blk & 1;
    const int st  = (blk >> 1) & 15;
    const int b   = blk >> 5;
    const int s0  = st << 6;
    const int tid = threadIdx.x;
    const int l   = tid & 63;
    const int w   = tid >> 6;
    const int lr  = l & 15;
    const int lk  = l >> 4;

    const float* keyB = Key + ((size_t)b << 20) + (kc << 9);
    const short* wgtW = wgtA + (((size_t)b * 384 + (kc << 6)) << 7) + lk * 128 + lr * 8;

    // staging geometry: thread -> (rows r0, r0+32 [, 64+r0 if tid<16], col-group j8)
    const int j8 = tid & 7;
    const int r0 = tid >> 3;                 // 0..31
    const int srow0 = s0 - 1 + r0;
    const int srow1 = s0 + 31 + r0;          // always in [31,1022]
    const int srow2 = s0 + 63 + r0;          // tid<16 only (r0 in {0,1})
    const bool ok0 = (srow0 >= 0);
    const bool ok2 = (tid < 16) && (srow2 < 1024);
    const f32x4* q0 = (const f32x4*)(keyB + (size_t)(ok0 ? srow0 : 0) * 1024 + j8 * 8);
    const f32x4* q1 = (const f32x4*)(keyB + (size_t)srow1 * 1024 + j8 * 8);
    const f32x4* q2 = (const f32x4*)(keyB + (size_t)(ok2 ? srow2 : 0) * 1024 + j8 * 8);

    const f32x4 z4 = (f32x4){0.f, 0.f, 0.f, 0.f};
    f32x4 vA0, vA1, vB0, vB1, vC0, vC1;

    // prologue: stage chunk 0 into buf 0
    vA0 = ok0 ? q0[0] : z4;  vA1 = ok0 ? q0[1] : z4;
    vB0 = q1[0];             vB1 = q1[1];
    vC0 = ok2 ? q2[0] : z4;  vC1 = ok2 ? q2[1] : z4;
    *(bf16x8*)&klds[0][r0][j8 * 8]      = pack8(vA0, vA1);
    *(bf16x8*)&klds[0][r0 + 32][j8 * 8] = pack8(vB0, vB1);
    if (tid < 16) *(bf16x8*)&klds[0][64 + r0][j8 * 8] = pack8(vC0, vC1);
    __syncthreads();

    f32x4 acc = z4;

    #pragma unroll 2
    for (int c = 0; c < 8; ++c) {
        const int buf = c & 1;
        const bool pre = (c + 1 < 8);
        if (pre) {   // issue next-chunk loads early; held in regs, used after barrier
            const int o = (c + 1) * 16;
            vA0 = ok0 ? q0[o] : z4;  vA1 = ok0 ? q0[o + 1] : z4;
            vB0 = q1[o];             vB1 = q1[o + 1];
            vC0 = ok2 ? q2[o] : z4;  vC1 = ok2 ? q2[o + 1] : z4;
        }
        #pragma unroll
        for (int k = 0; k < 3; ++k) {
            #pragma unroll
            for (int d2 = 0; d2 < 2; ++d2) {
                bf16x8 a  = *(const bf16x8*)(wgtW + (size_t)k * 16384 + (c * 8 + d2 * 4) * 128);
                bf16x8 kv = *(const bf16x8*)(&klds[buf][w * 16 + lr + k][d2 * 32 + lk * 8]);
                acc = __builtin_amdgcn_mfma_f32_16x16x32_bf16(a, kv, acc, 0, 0, 0);
            }
        }
        __syncthreads();
        if (pre) {
            *(bf16x8*)&klds[buf ^ 1][r0][j8 * 8]      = pack8(vA0, vA1);
            *(bf16x8*)&klds[buf ^ 1][r0 + 32][j8 * 8] = pack8(vB0, vB1);
            if (tid < 16) *(bf16x8*)&klds[buf ^ 1][64 + r0][j8 * 8] = pack8(vC0, vC1);
            __syncthreads();
        }
    }

    const int s = s0 + w * 16 + lr;
    #pragma unroll
    for (int r = 0; r < 4; ++r) {
        int h = lk * 4 + r;
        atomicAdd(&out[(((b << 4) + h) << 10) + s], acc[r]);
    }
}

extern "C" void kernel_launch(void* const* d_in, const int* in_sizes, int n_in,
                              void* d_out, int out_size, void* d_ws, size_t ws_size,
                              hipStream_t stream) {
    const float* Q  = (const float*)d_in[0];
    const float* K  = (const float*)d_in[1];
    const float* Wq = (const float*)d_in[4];
    const float* bq = (const float*)d_in[5];
    float* outp = (float*)d_out;

    short* wfrag = (short*)d_ws;                      // 98304 B
    short* wgtA  = (short*)((char*)d_ws + 98304);     // 3145728 B

    hipMemsetAsync(outp, 0, (size_t)out_size * sizeof(float), stream);
    hipLaunchKernelGGL(prep_wfrag, dim3(192),  dim3(256), 0, stream, Wq, wfrag);
    hipLaunchKernelGGL(qk_gemm,    dim3(512),  dim3(256), 0, stream, Q, wfrag, bq, wgtA);
    hipLaunchKernelGGL(conv_mfma,  dim3(1024), dim3(256), 0, stream, K, wgtA, outp);
}

// Round 4
// 66.445 us; speedup vs baseline: 1.5469x; 1.0056x over previous
//
#include <hip/hip_runtime.h>
#include <hip/hip_bf16.h>
#include <stdint.h>

typedef __attribute__((ext_vector_type(8))) short bf16x8;
typedef __attribute__((ext_vector_type(4))) float f32x4;

__device__ __forceinline__ short f2bf(float x) {
    __hip_bfloat16 h = __float2bfloat16(x);   // native cvt on gfx950 (RNE)
    return __builtin_bit_cast(short, h);
}

__device__ __forceinline__ bf16x8 pack8(f32x4 a, f32x4 b) {
    bf16x8 r;
    r[0] = f2bf(a[0]); r[1] = f2bf(a[1]); r[2] = f2bf(a[2]); r[3] = f2bf(a[3]);
    r[4] = f2bf(b[0]); r[5] = f2bf(b[1]); r[6] = f2bf(b[2]); r[7] = f2bf(b[3]);
    return r;
}

// ---------------------------------------------------------------------------
// Kernel C: repack Wq (1024x48 f32) into bf16 B-fragment layout.
// ---------------------------------------------------------------------------
__global__ __launch_bounds__(256) void prep_wfrag(const float* __restrict__ Wq,
                                                  short* __restrict__ wfrag) {
    int idx = blockIdx.x * 256 + threadIdx.x;   // 0..49151
    int j    = idx & 7;
    int lane = (idx >> 3) & 63;
    int grp  = idx >> 9;          // ks*3+nf
    int nf   = grp % 3;
    int ks   = grp / 3;
    int k = ks * 32 + ((lane >> 4) << 3) + j;
    int n = nf * 16 + (lane & 15);
    wfrag[idx] = f2bf(Wq[k * 48 + n]);
}

// ---------------------------------------------------------------------------
// Kernel A: qk = Q @ Wq + bq  (M=32768, N=48, K=1024), MFMA 16x16x32 bf16.
// Epilogue scatter-stores bf16 weights into A-frag-friendly layout:
//   wgtA[b][k][dg(128)][h(16)][8]  (dg = d>>3, j = d&7)
// ---------------------------------------------------------------------------
__global__ __launch_bounds__(256) void qk_gemm(const float* __restrict__ Q,
                                               const short* __restrict__ wfrag,
                                               const float* __restrict__ bq,
                                               short* __restrict__ wgtA) {
    const int l  = threadIdx.x & 63;
    const int w  = threadIdx.x >> 6;
    const int lr = l & 15;
    const int lk = l >> 4;
    const int row0 = blockIdx.x * 64 + w * 16;

    f32x4 acc[3];
    acc[0] = (f32x4){0.f, 0.f, 0.f, 0.f};
    acc[1] = acc[0];
    acc[2] = acc[0];

    const float* qbase = Q + (size_t)(row0 + lr) * 1024 + lk * 8;

    #pragma unroll 4
    for (int ks = 0; ks < 32; ++ks) {
        const float* p = qbase + ks * 32;
        f32x4 q0 = *(const f32x4*)p;
        f32x4 q1 = *(const f32x4*)(p + 4);
        bf16x8 a = pack8(q0, q1);
        const bf16x8* wp = (const bf16x8*)(wfrag + (size_t)ks * 1536 + l * 8);
        acc[0] = __builtin_amdgcn_mfma_f32_16x16x32_bf16(a, wp[0],   acc[0], 0, 0, 0);
        acc[1] = __builtin_amdgcn_mfma_f32_16x16x32_bf16(a, wp[64],  acc[1], 0, 0, 0);
        acc[2] = __builtin_amdgcn_mfma_f32_16x16x32_bf16(a, wp[128], acc[2], 0, 0, 0);
    }

    #pragma unroll
    for (int nf = 0; nf < 3; ++nf) {
        int n = nf * 16 + lr;
        float bias = bq[n];
        int t  = n / 3;
        int kk = n - t * 3;
        #pragma unroll
        for (int r = 0; r < 4; ++r) {
            int row = row0 + lk * 4 + r;
            int b   = row >> 10;
            int h   = (row >> 6) & 15;
            int sp  = row & 63;
            int dg  = sp * 2 + (t >> 3);
            int j   = t & 7;
            wgtA[(((size_t)(b * 3 + kk) * 128 + dg) << 7) + h * 8 + j] = f2bf(acc[nf][r] + bias);
        }
    }
}

// ---------------------------------------------------------------------------
// Kernel B v4: conv-as-GEMM, LDS-staged keys, double-buffered, async-split
// staging. Grid: 32 b x 16 s-tiles x 4 d-quarters = 2048 blocks, 256 thr,
// 6 blocks/CU. Each wave: 16h x 16s, K'=768 (4 chunks of 64 d).
// Partial sums atomicAdd'ed into zeroed out.
// ---------------------------------------------------------------------------
__global__ __launch_bounds__(256, 6) void conv_mfma(const float* __restrict__ Key,
                                                    const short* __restrict__ wgtA,
                                                    float* __restrict__ out) {
    __shared__ short klds[2][66][72];   // 19008 B, row shift 4 banks: conflict-free
    const int blk = blockIdx.x;
    const int kc  = blk & 3;            // d-quarter
    const int st  = (blk >> 2) & 15;
    const int b   = blk >> 6;
    const int s0  = st << 6;
    const int tid = threadIdx.x;
    const int l   = tid & 63;
    const int w   = tid >> 6;
    const int lr  = l & 15;
    const int lk  = l >> 4;

    const float* keyB = Key + ((size_t)b << 20) + (kc << 8);            // +kc*256 floats
    const short* wgtW = wgtA + (((size_t)b * 384 + (kc << 5)) << 7) + lk * 128 + lr * 8;

    // staging geometry: thread -> (rows r0, r0+32 [, 64+r0 if tid<16], col-group j8)
    const int j8 = tid & 7;
    const int r0 = tid >> 3;                 // 0..31
    const int srow0 = s0 - 1 + r0;
    const int srow1 = s0 + 31 + r0;          // always in [31,1022]
    const int srow2 = s0 + 63 + r0;          // tid<16 only (r0 in {0,1})
    const bool ok0 = (srow0 >= 0);
    const bool ok2 = (tid < 16) && (srow2 < 1024);
    const f32x4* q0 = (const f32x4*)(keyB + (size_t)(ok0 ? srow0 : 0) * 1024 + j8 * 8);
    const f32x4* q1 = (const f32x4*)(keyB + (size_t)srow1 * 1024 + j8 * 8);
    const f32x4* q2 = (const f32x4*)(keyB + (size_t)(ok2 ? srow2 : 0) * 1024 + j8 * 8);

    const f32x4 z4 = (f32x4){0.f, 0.f, 0.f, 0.f};

    // prologue: stage chunk 0 into buf 0
    {
        f32x4 a0 = ok0 ? q0[0] : z4, a1 = ok0 ? q0[1] : z4;
        f32x4 b0 = q1[0],            b1 = q1[1];
        f32x4 c0 = ok2 ? q2[0] : z4, c1 = ok2 ? q2[1] : z4;
        *(bf16x8*)&klds[0][r0][j8 * 8]      = pack8(a0, a1);
        *(bf16x8*)&klds[0][r0 + 32][j8 * 8] = pack8(b0, b1);
        if (tid < 16) *(bf16x8*)&klds[0][64 + r0][j8 * 8] = pack8(c0, c1);
    }
    __syncthreads();

    f32x4 acc = z4;

    #pragma unroll
    for (int c = 0; c < 4; ++c) {
        const int buf = c & 1;
        const bool pre = (c + 1 < 4);
        f32x4 a0, a1, b0, b1, c0, c1;
        if (pre) {   // issue next-chunk loads early; used after barrier
            const int o = (c + 1) * 16;
            a0 = ok0 ? q0[o] : z4;  a1 = ok0 ? q0[o + 1] : z4;
            b0 = q1[o];             b1 = q1[o + 1];
            c0 = ok2 ? q2[o] : z4;  c1 = ok2 ? q2[o + 1] : z4;
        }
        #pragma unroll
        for (int k = 0; k < 3; ++k) {
            #pragma unroll
            for (int d2 = 0; d2 < 2; ++d2) {
                bf16x8 a  = *(const bf16x8*)(wgtW + (size_t)k * 16384 + (c * 8 + d2 * 4) * 128);
                bf16x8 kv = *(const bf16x8*)(&klds[buf][w * 16 + lr + k][d2 * 32 + lk * 8]);
                acc = __builtin_amdgcn_mfma_f32_16x16x32_bf16(a, kv, acc, 0, 0, 0);
            }
        }
        if (pre) {
            // convert before barrier: only 12 VGPRs (bf16) live across it
            bf16x8 wA = pack8(a0, a1);
            bf16x8 wB = pack8(b0, b1);
            bf16x8 wC = pack8(c0, c1);
            __syncthreads();
            *(bf16x8*)&klds[buf ^ 1][r0][j8 * 8]      = wA;
            *(bf16x8*)&klds[buf ^ 1][r0 + 32][j8 * 8] = wB;
            if (tid < 16) *(bf16x8*)&klds[buf ^ 1][64 + r0][j8 * 8] = wC;
            __syncthreads();
        }
    }

    const int s = s0 + w * 16 + lr;
    #pragma unroll
    for (int r = 0; r < 4; ++r) {
        int h = lk * 4 + r;
        atomicAdd(&out[(((b << 4) + h) << 10) + s], acc[r]);
    }
}

extern "C" void kernel_launch(void* const* d_in, const int* in_sizes, int n_in,
                              void* d_out, int out_size, void* d_ws, size_t ws_size,
                              hipStream_t stream) {
    const float* Q  = (const float*)d_in[0];
    const float* K  = (const float*)d_in[1];
    const float* Wq = (const float*)d_in[4];
    const float* bq = (const float*)d_in[5];
    float* outp = (float*)d_out;

    short* wfrag = (short*)d_ws;                      // 98304 B
    short* wgtA  = (short*)((char*)d_ws + 98304);     // 3145728 B

    hipMemsetAsync(outp, 0, (size_t)out_size * sizeof(float), stream);
    hipLaunchKernelGGL(prep_wfrag, dim3(192),  dim3(256), 0, stream, Wq, wfrag);
    hipLaunchKernelGGL(qk_gemm,    dim3(512),  dim3(256), 0, stream, Q, wfrag, bq, wgtA);
    hipLaunchKernelGGL(conv_mfma,  dim3(2048), dim3(256), 0, stream, K, wgtA, outp);
}

// Round 5
// 65.631 us; speedup vs baseline: 1.5660x; 1.0124x over previous
//
#include <hip/hip_runtime.h>
#include <hip/hip_bf16.h>
#include <stdint.h>

typedef __attribute__((ext_vector_type(8))) short bf16x8;
typedef __attribute__((ext_vector_type(4))) float f32x4;

__device__ __forceinline__ short f2bf(float x) {
    __hip_bfloat16 h = __float2bfloat16(x);   // native cvt on gfx950 (RNE)
    return __builtin_bit_cast(short, h);
}

__device__ __forceinline__ bf16x8 pack8(f32x4 a, f32x4 b) {
    bf16x8 r;
    r[0] = f2bf(a[0]); r[1] = f2bf(a[1]); r[2] = f2bf(a[2]); r[3] = f2bf(a[3]);
    r[4] = f2bf(b[0]); r[5] = f2bf(b[1]); r[6] = f2bf(b[2]); r[7] = f2bf(b[3]);
    return r;
}

// ---------------------------------------------------------------------------
// Kernel C: repack Wq (1024x48 f32) into bf16 B-fragment layout.
// ---------------------------------------------------------------------------
__global__ __launch_bounds__(256) void prep_wfrag(const float* __restrict__ Wq,
                                                  short* __restrict__ wfrag) {
    int idx = blockIdx.x * 256 + threadIdx.x;   // 0..49151
    int j    = idx & 7;
    int lane = (idx >> 3) & 63;
    int grp  = idx >> 9;          // ks*3+nf
    int nf   = grp % 3;
    int ks   = grp / 3;
    int k = ks * 32 + ((lane >> 4) << 3) + j;
    int n = nf * 16 + (lane & 15);
    wfrag[idx] = f2bf(Wq[k * 48 + n]);
}

// ---------------------------------------------------------------------------
// Kernel A: qk = Q @ Wq + bq  (M=32768, N=48, K=1024), MFMA 16x16x32 bf16.
// Epilogue scatter-stores bf16 weights into A-frag-friendly layout:
//   wgtA[b][k][dg(128)][h(16)][8]  (dg = d>>3, j = d&7)
// ---------------------------------------------------------------------------
__global__ __launch_bounds__(256) void qk_gemm(const float* __restrict__ Q,
                                               const short* __restrict__ wfrag,
                                               const float* __restrict__ bq,
                                               short* __restrict__ wgtA) {
    const int l  = threadIdx.x & 63;
    const int w  = threadIdx.x >> 6;
    const int lr = l & 15;
    const int lk = l >> 4;
    const int row0 = blockIdx.x * 64 + w * 16;

    f32x4 acc[3];
    acc[0] = (f32x4){0.f, 0.f, 0.f, 0.f};
    acc[1] = acc[0];
    acc[2] = acc[0];

    const float* qbase = Q + (size_t)(row0 + lr) * 1024 + lk * 8;

    #pragma unroll 4
    for (int ks = 0; ks < 32; ++ks) {
        const float* p = qbase + ks * 32;
        f32x4 q0 = *(const f32x4*)p;
        f32x4 q1 = *(const f32x4*)(p + 4);
        bf16x8 a = pack8(q0, q1);
        const bf16x8* wp = (const bf16x8*)(wfrag + (size_t)ks * 1536 + l * 8);
        acc[0] = __builtin_amdgcn_mfma_f32_16x16x32_bf16(a, wp[0],   acc[0], 0, 0, 0);
        acc[1] = __builtin_amdgcn_mfma_f32_16x16x32_bf16(a, wp[64],  acc[1], 0, 0, 0);
        acc[2] = __builtin_amdgcn_mfma_f32_16x16x32_bf16(a, wp[128], acc[2], 0, 0, 0);
    }

    #pragma unroll
    for (int nf = 0; nf < 3; ++nf) {
        int n = nf * 16 + lr;
        float bias = bq[n];
        int t  = n / 3;
        int kk = n - t * 3;
        #pragma unroll
        for (int r = 0; r < 4; ++r) {
            int row = row0 + lk * 4 + r;
            int b   = row >> 10;
            int h   = (row >> 6) & 15;
            int sp  = row & 63;
            int dg  = sp * 2 + (t >> 3);
            int j   = t & 7;
            wgtA[(((size_t)(b * 3 + kk) * 128 + dg) << 7) + h * 8 + j] = f2bf(acc[nf][r] + bias);
        }
    }
}

// ---------------------------------------------------------------------------
// Kernel B v5: conv-as-GEMM. Grid 32b x 32 s-tiles = 1024 blocks, 256 thr.
// s-tile 32. 4 waves: w&1 = s-sub (16 cols), w>>1 = d-half (512 d each).
// Per step t (8 steps): stage 34 rows x 128 d (64 from each half) f32->bf16
// into XOR-swizzled LDS, double-buffered, loads issued one step early.
// d-halves combined via LDS reduction; plain coalesced stores. NO atomics.
// ---------------------------------------------------------------------------
__global__ __launch_bounds__(256, 4) void conv_mfma(const float* __restrict__ Key,
                                                    const short* __restrict__ wgtA,
                                                    float* __restrict__ out) {
    __shared__ short klds[2][34][128];   // linear 256B rows; byte ^= (row&7)<<4
    __shared__ float red[2][16][17];
    const int blk = blockIdx.x;
    const int st  = blk & 31;
    const int b   = blk >> 5;
    const int s0  = st << 5;
    const int tid = threadIdx.x;
    const int l   = tid & 63;
    const int w   = tid >> 6;
    const int lr  = l & 15;
    const int lk  = l >> 4;
    const int ss  = w & 1;     // s-sub-tile
    const int dh  = w >> 1;    // d-half

    // staging geometry: jg = tid&15 -> 8-float column group; r = tid>>4 ->
    // rows r, r+16, and (r<2) r+32.   d offset: (jg&7)*8 + (jg>>3)*512 (+ t*64)
    const int jg = tid & 15;
    const int r  = tid >> 4;
    const int dcol = ((jg & 7) << 3) + ((jg >> 3) << 9);
    const float* keyB = Key + ((size_t)b << 20) + dcol;

    const bool g0 = (s0 - 1 + r) >= 0;
    const bool g2 = (r < 2) && (s0 + 31 + r < 1024);
    const float* p0 = keyB + (size_t)(g0 ? s0 - 1 + r : 0) * 1024;
    const float* p1 = keyB + (size_t)(s0 + 15 + r) * 1024;
    const float* p2 = keyB + (size_t)(g2 ? s0 + 31 + r : 0) * 1024;

    const int row0 = r, row1 = r + 16, row2 = r + 32;
    char* ldsB = (char*)&klds[0][0][0];

    #define STB(buf, row, v) \
        *(bf16x8*)(ldsB + ((buf) * 34 + (row)) * 256 + ((jg * 16) ^ (((row) & 7) << 4))) = (v)

    const f32x4 z4 = (f32x4){0.f, 0.f, 0.f, 0.f};
    f32x4 a0, a1, b0, b1, c0, c1;

    // prologue: load+write step 0, then issue step-1 loads
    a0 = g0 ? p0[0] : 0.f, a0 = g0 ? *(const f32x4*)p0 : z4;
    a1 = g0 ? *(const f32x4*)(p0 + 4) : z4;
    b0 = *(const f32x4*)p1;       b1 = *(const f32x4*)(p1 + 4);
    c0 = g2 ? *(const f32x4*)p2 : z4;
    c1 = g2 ? *(const f32x4*)(p2 + 4) : z4;
    STB(0, row0, pack8(a0, a1));
    STB(0, row1, pack8(b0, b1));
    if (r < 2) STB(0, row2, pack8(c0, c1));
    a0 = g0 ? *(const f32x4*)(p0 + 64) : z4;
    a1 = g0 ? *(const f32x4*)(p0 + 68) : z4;
    b0 = *(const f32x4*)(p1 + 64);  b1 = *(const f32x4*)(p1 + 68);
    c0 = g2 ? *(const f32x4*)(p2 + 64) : z4;
    c1 = g2 ? *(const f32x4*)(p2 + 68) : z4;
    __syncthreads();

    // per-lane wgt base: wgtA[((b*3+k)*128 + dg)*128 + lr*8], dg = dh*64+t*8+kk*4+lk
    const short* wgtW = wgtA + (((size_t)b * 384 + (dh << 6) + lk) << 7) + lr * 8;

    f32x4 acc = z4;

    #pragma unroll
    for (int t = 0; t < 8; ++t) {
        const int buf = t & 1;
        #pragma unroll
        for (int k = 0; k < 3; ++k) {
            const int row = ss * 16 + lr + k;
            const char* rb = ldsB + (buf * 34 + row) * 256;
            const int sw = ((row & 7) << 4);
            #pragma unroll
            for (int kk = 0; kk < 2; ++kk) {
                bf16x8 kv = *(const bf16x8*)(rb + ((((dh << 7) + (kk << 6) + (lk << 4))) ^ sw));
                bf16x8 a  = *(const bf16x8*)(wgtW + k * 16384 + t * 1024 + kk * 512);
                acc = __builtin_amdgcn_mfma_f32_16x16x32_bf16(a, kv, acc, 0, 0, 0);
            }
        }
        if (t < 7) {
            bf16x8 wA = pack8(a0, a1);
            bf16x8 wB = pack8(b0, b1);
            bf16x8 wC = pack8(c0, c1);
            __syncthreads();
            STB(buf ^ 1, row0, wA);
            STB(buf ^ 1, row1, wB);
            if (r < 2) STB(buf ^ 1, row2, wC);
            if (t < 6) {   // issue loads for step t+2; in flight across next compute
                const int o = (t + 2) << 6;
                a0 = g0 ? *(const f32x4*)(p0 + o) : z4;
                a1 = g0 ? *(const f32x4*)(p0 + o + 4) : z4;
                b0 = *(const f32x4*)(p1 + o);  b1 = *(const f32x4*)(p1 + o + 4);
                c0 = g2 ? *(const f32x4*)(p2 + o) : z4;
                c1 = g2 ? *(const f32x4*)(p2 + o + 4) : z4;
            }
            __syncthreads();
        }
    }
    #undef STB

    // combine d-halves: dh=1 waves push partials through LDS, dh=0 stores.
    if (dh == 1) {
        #pragma unroll
        for (int r4 = 0; r4 < 4; ++r4) red[ss][lk * 4 + r4][lr] = acc[r4];
    }
    __syncthreads();
    if (dh == 0) {
        const int s = s0 + ss * 16 + lr;
        #pragma unroll
        for (int r4 = 0; r4 < 4; ++r4) {
            int h = lk * 4 + r4;
            out[(((b << 4) + h) << 10) + s] = acc[r4] + red[ss][h][lr];
        }
    }
}

extern "C" void kernel_launch(void* const* d_in, const int* in_sizes, int n_in,
                              void* d_out, int out_size, void* d_ws, size_t ws_size,
                              hipStream_t stream) {
    const float* Q  = (const float*)d_in[0];
    const float* K  = (const float*)d_in[1];
    const float* Wq = (const float*)d_in[4];
    const float* bq = (const float*)d_in[5];
    float* outp = (float*)d_out;

    short* wfrag = (short*)d_ws;                      // 98304 B
    short* wgtA  = (short*)((char*)d_ws + 98304);     // 3145728 B

    hipLaunchKernelGGL(prep_wfrag, dim3(192),  dim3(256), 0, stream, Wq, wfrag);
    hipLaunchKernelGGL(qk_gemm,    dim3(512),  dim3(256), 0, stream, Q, wfrag, bq, wgtA);
    hipLaunchKernelGGL(conv_mfma,  dim3(1024), dim3(256), 0, stream, K, wgtA, outp);
}